// Round 11
// baseline (568.133 us; speedup 1.0000x reference)
//
#include <hip/hip_runtime.h>

#define MM    12
#define TSOL  64
#define NXX   256
#define NYY   256
#define NTT   50
#define NOUTT 256
#define ICH   8     // i-rows per block -> 8KB contiguous per (m,ch) stream
#define RPW   2     // i-rows per wave (half of R10: keeps VGPR under 128)

typedef float f4v __attribute__((ext_vector_type(4)));

// Nontemporal float4 load/store: stream past L1 allocation. Src has zero
// intra-invocation reuse and out is write-once. R7 proved NT loads lift the
// ~2.8 TB/s cached-read wall. v11 = clean run-length probe (8KB runs) with
// the VGPR blow-up that confounded R10 capped out by design.
__device__ __forceinline__ f4v nt4(const float* p) {
    return __builtin_nontemporal_load((const f4v*)p);
}
__device__ __forceinline__ void nt4st(float* p, f4v v) {
    __builtin_nontemporal_store(v, (f4v*)p);
}

// Compressed stencil: per (m,k) ONE float c. Contribution of source m at
// output k:  w[m]*src[k] + |c|*(src[k+sgn(c)] - src[k]),  where
// c = (iy==k) ? +w*ty : -(w*(1-ty)). Exact up to 1ulp regrouping (<=2e-10).
// w[m] is a per-m scalar; k=255 uses w255[m] (inb knife edge).
__device__ float g_c[MM * NOUTT];
__device__ float g_w[MM];
__device__ float g_w255[MM];

// grid: MM blocks x 256 threads. Block m computes table row m.
__global__ __launch_bounds__(256) void ai_setup_kernel(
    const float* __restrict__ params,
    const float* __restrict__ Wq, const float* __restrict__ bq,
    const float* __restrict__ Wk, const float* __restrict__ bk)
{
    const int k = threadIdx.x;
    const int m = blockIdx.x;

    __shared__ float s_attn[MM][4];
    __shared__ float s_sw[MM];
    __shared__ float s_wm;
    __shared__ float s_ys[NYY];

    if (k < MM) {
        float ly = params[k * 3 + 0];
        float p0 = (ly - 30.0f) / 90.0f;
        float p1 = params[k * 3 + 1] / 0.0029f;
        float p2 = params[k * 3 + 2] / 0.0018f;
        const float t0 = 0.5f;                 // (75-30)/90 exact
        const float t1 = 0.001f / 0.0029f;
        const float t2 = 0.0001f / 0.0018f;
        for (int h = 0; h < 4; ++h) {
            float acc = 0.0f;
            for (int d = 0; d < 8; ++d) {
                int o = h * 8 + d;
                float q  = t0 * Wq[o * 3 + 0] + t1 * Wq[o * 3 + 1] + t2 * Wq[o * 3 + 2] + bq[o];
                float kv = p0 * Wk[o * 3 + 0] + p1 * Wk[o * 3 + 1] + p2 * Wk[o * 3 + 2] + bk[o];
                acc += kv * q;
            }
            s_attn[k][h] = acc * 0.35355339059327373f;  // 1/sqrt(8)
        }
        float d0 = (p0 - t0) / 0.25f;
        float d1 = (p1 - t1) / 0.25f;
        float d2 = (p2 - t2) / 0.25f;
        s_sw[k] = expf(-(d0 * d0 + d1 * d1 + d2 * d2) * 0.5f);
    }
    __syncthreads();

    if (k == 0) {
        float aw[MM];
        for (int j = 0; j < MM; ++j) aw[j] = 0.0f;
        for (int h = 0; h < 4; ++h) {               // softmax over m, per head
            float mx = s_attn[0][h];
            for (int j = 1; j < MM; ++j) mx = fmaxf(mx, s_attn[j][h]);
            float e[MM]; float sum = 0.0f;
            for (int j = 0; j < MM; ++j) { e[j] = expf(s_attn[j][h] - mx); sum += e[j]; }
            for (int j = 0; j < MM; ++j) aw[j] += e[j] / sum;
        }
        float swsum = 0.0f;
        for (int j = 0; j < MM; ++j) swsum += s_sw[j];
        float wj[MM]; float wsum = 0.0f;
        for (int j = 0; j < MM; ++j) {
            wj[j] = (aw[j] * 0.25f) * (s_sw[j] / swsum);
            wsum += wj[j];
        }
        s_wm = wj[m] / wsum;
    }

    // ys row for this m — EXACT fp32 op sequence of the reference:
    // ys[j] = fl( fl(l01[j]*ly) * fl(75/ly) ),  l01[j] = fl(j * fl(1/255))
    {
        float ly  = params[m * 3 + 0];
        float inv = 75.0f / ly;                    // IEEE divide (no fast-math)
        float l01 = (float)k * (1.0f / 255.0f);
        s_ys[k] = (l01 * ly) * inv;
    }
    __syncthreads();

    float w  = s_wm;
    float yq = (float)k * (75.0f / 255.0f);        // rounds to exactly 75.0 at k=255
    // upper_bound: largest j with ys[j] <= yq  (== searchsorted 'right' - 1)
    int l = 0, r = NYY;
    while (l < r) { int mid = (l + r) >> 1; if (s_ys[mid] <= yq) l = mid + 1; else r = mid; }
    int iy = l - 1;
    iy = iy < 0 ? 0 : (iy > NYY - 2 ? NYY - 2 : iy);
    float ty  = (yq - s_ys[iy]) / (s_ys[iy + 1] - s_ys[iy]);
    bool  inb = (yq >= s_ys[0]) && (yq <= s_ys[NYY - 1]);   // the k=255 knife edge
    float a = inb ? w * (1.0f - ty) : 0.0f;        // weight on src[iy]
    float b = inb ? w * ty          : 0.0f;        // weight on src[iy+1]
    // iy is exactly k or k-1 (ys ~= k*75/255 up to 2 ulp, monotone).
    bool sel = (iy == k);
    // sign of c encodes neighbor: +c -> k+1 (weight b), -c -> k-1 (weight a).
    g_c[m * NOUTT + k] = sel ? b : -a;             // -0.0f keeps direction
    if (k == 0)   g_w[m]    = w;                   // inb always true for k<255
    if (k == 255) g_w255[m] = inb ? w : 0.0f;
}

// grid: (NOUTT/ICH, NTT) = (32, 50) = 1600 blocks, block 256 = 4 waves.
// Block owns (t, 8 consecutive i-rows): per (m,ch) it reads 8KB CONTIGUOUS
// (vs 4KB in R9) -- run-length probe with R10's VGPR confound removed:
// wave owns 2 rows (staging 8 f4v = 32 VGPR, acc 16 VGPR) and
// __launch_bounds__(256,4) hard-caps allocation at 128 VGPR.
// m-pipeline 2-deep double-buffered NT loads; table in LDS (barrier drains
// only the 3 L2-hot DMAs); NT stores.
__global__ __launch_bounds__(256, 4) void ai_resample_kernel(
    const float* __restrict__ c1, const float* __restrict__ c2,
    float* __restrict__ out)
{
    __shared__ float s_c[MM * NOUTT];          // 12 KB

    const int tid  = threadIdx.x;
    const int lane = tid & 63;
    const int wv   = tid >> 6;
    const int t    = blockIdx.y;
    int tsrc = (t * TSOL) / (NTT - 1);         // floor(t*64/49), fp-robust
    if (tsrc > TSOL - 1) tsrc = TSOL - 1;
    const int i0   = blockIdx.x * ICH + wv * RPW;
    const int k0   = lane * 4;
    const bool l63 = (lane == 63);

    // Stage 12KB table: 3 chunks x (4 waves x 1KB), wave-uniform LDS base.
#pragma unroll
    for (int c = 0; c < 3; ++c) {
        const float* gp = g_c + c * 1024 + wv * 256 + lane * 4;
        float*       lp = s_c + c * 1024 + wv * 256;
        __builtin_amdgcn_global_load_lds(
            (const __attribute__((address_space(1))) void*)gp,
            (__attribute__((address_space(3))) void*)lp, 16, 0, 0);
    }

    // Per-m scalar weights (wave-uniform address -> s_load, SGPRs).
    float wmv[MM], w2v[MM];
#pragma unroll
    for (int m = 0; m < MM; ++m) { wmv[m] = g_w[m]; w2v[m] = g_w255[m]; }

    // Barrier drains only the 3 DMA ops (no NT loads issued yet).
    __syncthreads();

    const size_t SLAB = (size_t)TSOL * NXX * NYY;
    const size_t roff = (size_t)tsrc * (NXX * NYY) + (size_t)i0 * NYY + (size_t)k0;

    // Double-buffered staging: 2 x 2 rows x 2 channels = 32 VGPR.
    f4v sA[2][RPW], sB[2][RPW];

#pragma unroll
    for (int r = 0; r < RPW; ++r) sA[0][r] = nt4(c1 + roff + (size_t)r * NYY);
#pragma unroll
    for (int r = 0; r < RPW; ++r) sB[0][r] = nt4(c2 + roff + (size_t)r * NYY);

    float4 acc1[RPW], acc2[RPW];
#pragma unroll
    for (int r = 0; r < RPW; ++r) {
        acc1[r] = make_float4(0.f, 0.f, 0.f, 0.f);
        acc2[r] = make_float4(0.f, 0.f, 0.f, 0.f);
    }

#pragma unroll
    for (int m = 0; m < MM; ++m) {
        const int cur = m & 1;                 // compile-time after unroll
        const int nxt = cur ^ 1;
        if (m < MM - 1) {                      // issue next m's 4 NT loads
            const size_t b = (size_t)(m + 1) * SLAB + roff;
#pragma unroll
            for (int r = 0; r < RPW; ++r) sA[nxt][r] = nt4(c1 + b + (size_t)r * NYY);
#pragma unroll
            for (int r = 0; r < RPW; ++r) sB[nxt][r] = nt4(c2 + b + (size_t)r * NYY);
        }
        const float4 cc  = *(const float4*)&s_c[m * NOUTT + k0];
        const float  wm_ = wmv[m];
        const float  w_w = l63 ? w2v[m] : wm_; // k=255 knife edge
#pragma unroll
        for (int r = 0; r < RPW; ++r) {
            f4v s = sA[cur][r];
            float lft = __shfl_up(s.w, 1);     // src[k0-1]; lane0: weight +0
            float rgt = __shfl_down(s.x, 1);   // src[k0+4]; lane63: weight -0
            acc1[r].x += wm_ * s.x + fabsf(cc.x) * (((__float_as_int(cc.x) >= 0) ? s.y : lft) - s.x);
            acc1[r].y += wm_ * s.y + fabsf(cc.y) * (((__float_as_int(cc.y) >= 0) ? s.z : s.x) - s.y);
            acc1[r].z += wm_ * s.z + fabsf(cc.z) * (((__float_as_int(cc.z) >= 0) ? s.w : s.y) - s.z);
            acc1[r].w += w_w * s.w + fabsf(cc.w) * (((__float_as_int(cc.w) >= 0) ? rgt : s.z) - s.w);
            s = sB[cur][r];
            lft = __shfl_up(s.w, 1);
            rgt = __shfl_down(s.x, 1);
            acc2[r].x += wm_ * s.x + fabsf(cc.x) * (((__float_as_int(cc.x) >= 0) ? s.y : lft) - s.x);
            acc2[r].y += wm_ * s.y + fabsf(cc.y) * (((__float_as_int(cc.y) >= 0) ? s.z : s.x) - s.y);
            acc2[r].z += wm_ * s.z + fabsf(cc.z) * (((__float_as_int(cc.z) >= 0) ? s.w : s.y) - s.z);
            acc2[r].w += w_w * s.w + fabsf(cc.w) * (((__float_as_int(cc.w) >= 0) ? rgt : s.z) - s.w);
        }
    }

#pragma unroll
    for (int r = 0; r < RPW; ++r) {
        const int i = i0 + r;
        float4 a1 = acc1[r], a2 = acc2[r];
        if (lane == 0) a1.x = 0.001f;          // c1[:,:,0]  = C_CU_TARGET
        if (l63)       a2.w = 0.0001f;         // c2[:,:,-1] = C_NI_TARGET
        nt4st(&out[((size_t)t * NOUTT + (size_t)i) * NOUTT + (size_t)k0],
              (f4v){a1.x, a1.y, a1.z, a1.w});
        nt4st(&out[((size_t)(NTT + t) * NOUTT + (size_t)i) * NOUTT + (size_t)k0],
              (f4v){a2.x, a2.y, a2.z, a2.w});
    }
}

extern "C" void kernel_launch(void* const* d_in, const int* in_sizes, int n_in,
                              void* d_out, int out_size, void* d_ws, size_t ws_size,
                              hipStream_t stream) {
    const float* params = (const float*)d_in[0];
    const float* c1     = (const float*)d_in[1];
    const float* c2     = (const float*)d_in[2];
    const float* Wq     = (const float*)d_in[3];
    const float* bq     = (const float*)d_in[4];
    const float* Wk     = (const float*)d_in[5];
    const float* bk     = (const float*)d_in[6];
    float* out = (float*)d_out;

    ai_setup_kernel<<<dim3(MM), dim3(256), 0, stream>>>(params, Wq, bq, Wk, bk);
    ai_resample_kernel<<<dim3(NOUTT / ICH, NTT), dim3(256), 0, stream>>>(c1, c2, out);
}

// Round 12
// 380.599 us; speedup vs baseline: 1.4927x; 1.4927x over previous
//
#include <hip/hip_runtime.h>

#define MM    12
#define TSOL  64
#define NXX   256
#define NYY   256
#define NTT   50
#define NOUTT 256

typedef float f4v __attribute__((ext_vector_type(4)));

// Nontemporal float4 load/store: stream past L1 allocation. Src has zero
// intra-invocation reuse and out is write-once -- caching either is waste.
// R7 proved NT loads lift the ~2.8 TB/s cached-read wall (R0-R6 invariant).
__device__ __forceinline__ f4v nt4(const float* p) {
    return __builtin_nontemporal_load((const f4v*)p);
}
__device__ __forceinline__ void nt4st(float* p, f4v v) {
    __builtin_nontemporal_store(v, (f4v*)p);
}

// Compressed stencil: per (m,k) ONE float c. Contribution of source m at
// output k:  w[m]*src[k] + |c|*(src[k+sgn(c)] - src[k]),  where
// c = (iy==k) ? +w*ty : -(w*(1-ty)). Exact up to 1ulp regrouping (<=2e-10).
// w[m] is a per-m scalar; k=255 uses w255[m] (inb knife edge).
__device__ float g_c[MM * NOUTT];
__device__ float g_w[MM];
__device__ float g_w255[MM];

// grid: MM blocks x 256 threads. Block m computes table row m.
__global__ __launch_bounds__(256) void ai_setup_kernel(
    const float* __restrict__ params,
    const float* __restrict__ Wq, const float* __restrict__ bq,
    const float* __restrict__ Wk, const float* __restrict__ bk)
{
    const int k = threadIdx.x;
    const int m = blockIdx.x;

    __shared__ float s_attn[MM][4];
    __shared__ float s_sw[MM];
    __shared__ float s_wm;
    __shared__ float s_ys[NYY];

    if (k < MM) {
        float ly = params[k * 3 + 0];
        float p0 = (ly - 30.0f) / 90.0f;
        float p1 = params[k * 3 + 1] / 0.0029f;
        float p2 = params[k * 3 + 2] / 0.0018f;
        const float t0 = 0.5f;                 // (75-30)/90 exact
        const float t1 = 0.001f / 0.0029f;
        const float t2 = 0.0001f / 0.0018f;
        for (int h = 0; h < 4; ++h) {
            float acc = 0.0f;
            for (int d = 0; d < 8; ++d) {
                int o = h * 8 + d;
                float q  = t0 * Wq[o * 3 + 0] + t1 * Wq[o * 3 + 1] + t2 * Wq[o * 3 + 2] + bq[o];
                float kv = p0 * Wk[o * 3 + 0] + p1 * Wk[o * 3 + 1] + p2 * Wk[o * 3 + 2] + bk[o];
                acc += kv * q;
            }
            s_attn[k][h] = acc * 0.35355339059327373f;  // 1/sqrt(8)
        }
        float d0 = (p0 - t0) / 0.25f;
        float d1 = (p1 - t1) / 0.25f;
        float d2 = (p2 - t2) / 0.25f;
        s_sw[k] = expf(-(d0 * d0 + d1 * d1 + d2 * d2) * 0.5f);
    }
    __syncthreads();

    if (k == 0) {
        float aw[MM];
        for (int j = 0; j < MM; ++j) aw[j] = 0.0f;
        for (int h = 0; h < 4; ++h) {               // softmax over m, per head
            float mx = s_attn[0][h];
            for (int j = 1; j < MM; ++j) mx = fmaxf(mx, s_attn[j][h]);
            float e[MM]; float sum = 0.0f;
            for (int j = 0; j < MM; ++j) { e[j] = expf(s_attn[j][h] - mx); sum += e[j]; }
            for (int j = 0; j < MM; ++j) aw[j] += e[j] / sum;
        }
        float swsum = 0.0f;
        for (int j = 0; j < MM; ++j) swsum += s_sw[j];
        float wj[MM]; float wsum = 0.0f;
        for (int j = 0; j < MM; ++j) {
            wj[j] = (aw[j] * 0.25f) * (s_sw[j] / swsum);
            wsum += wj[j];
        }
        s_wm = wj[m] / wsum;
    }

    // ys row for this m — EXACT fp32 op sequence of the reference:
    // ys[j] = fl( fl(l01[j]*ly) * fl(75/ly) ),  l01[j] = fl(j * fl(1/255))
    {
        float ly  = params[m * 3 + 0];
        float inv = 75.0f / ly;                    // IEEE divide (no fast-math)
        float l01 = (float)k * (1.0f / 255.0f);
        s_ys[k] = (l01 * ly) * inv;
    }
    __syncthreads();

    float w  = s_wm;
    float yq = (float)k * (75.0f / 255.0f);        // rounds to exactly 75.0 at k=255
    // upper_bound: largest j with ys[j] <= yq  (== searchsorted 'right' - 1)
    int l = 0, r = NYY;
    while (l < r) { int mid = (l + r) >> 1; if (s_ys[mid] <= yq) l = mid + 1; else r = mid; }
    int iy = l - 1;
    iy = iy < 0 ? 0 : (iy > NYY - 2 ? NYY - 2 : iy);
    float ty  = (yq - s_ys[iy]) / (s_ys[iy + 1] - s_ys[iy]);
    bool  inb = (yq >= s_ys[0]) && (yq <= s_ys[NYY - 1]);   // the k=255 knife edge
    float a = inb ? w * (1.0f - ty) : 0.0f;        // weight on src[iy]
    float b = inb ? w * ty          : 0.0f;        // weight on src[iy+1]
    // iy is exactly k or k-1 (ys ~= k*75/255 up to 2 ulp, monotone).
    bool sel = (iy == k);
    // sign of c encodes neighbor: +c -> k+1 (weight b), -c -> k-1 (weight a).
    g_c[m * NOUTT + k] = sel ? b : -a;             // -0.0f keeps direction
    if (k == 0)   g_w[m]    = w;                   // inb always true for k<255
    if (k == 255) g_w255[m] = inb ? w : 0.0f;
}

// grid: (NOUTT/4, NTT) — the proven locality shape (12800 waves, ~10
// t-slabs LLC-resident). Wave wv owns output row i = 4*bx+wv for t = by.
// v8 (session best, 381.2us): NO LDS, NO barrier, table in VGPRs (cm[12],
// L2/L1-hot cached loads), per-m weights in SGPRs; ALL 24 NT source loads
// issued upfront (24KB/wave in flight) and consumed strictly in issue
// order so the compiler emits progressive vmcnt(N) with no drain anywhere.
// Stores nontemporal (write-once data, keep out of L2).
__global__ __launch_bounds__(256) void ai_resample_kernel(
    const float* __restrict__ c1, const float* __restrict__ c2,
    float* __restrict__ out)
{
    const int tid  = threadIdx.x;
    const int lane = tid & 63;
    const int wv   = tid >> 6;
    const int t    = blockIdx.y;
    const int i    = blockIdx.x * 4 + wv;
    int tsrc = (t * TSOL) / (NTT - 1);         // floor(t*64/49), fp-robust
    if (tsrc > TSOL - 1) tsrc = TSOL - 1;
    const int k0   = lane * 4;
    const bool l63 = (lane == 63);

    // Per-lane correction table: 12 float4, L2-hot cached loads, issued
    // first (consumed first -> progressive waits cover them cheaply).
    float4 cm[MM];
#pragma unroll
    for (int m = 0; m < MM; ++m) cm[m] = *(const float4*)&g_c[m * NOUTT + k0];

    // Per-m scalar weights (wave-uniform address -> s_load, SGPRs).
    float wmv[MM], w2v[MM];
#pragma unroll
    for (int m = 0; m < MM; ++m) { wmv[m] = g_w[m]; w2v[m] = g_w255[m]; }

    const size_t SLAB   = (size_t)TSOL * NXX * NYY;
    const size_t rowoff = (size_t)tsrc * (NXX * NYY) + (size_t)i * NYY + (size_t)k0;

    // Issue ALL 24 NT src loads upfront: 24KB/wave outstanding.
    f4v s1[MM], s2[MM];
#pragma unroll
    for (int m = 0; m < MM; ++m) s1[m] = nt4(c1 + (size_t)m * SLAB + rowoff);
#pragma unroll
    for (int m = 0; m < MM; ++m) s2[m] = nt4(c2 + (size_t)m * SLAB + rowoff);

    float4 acc1 = {0.f, 0.f, 0.f, 0.f};
    float4 acc2 = {0.f, 0.f, 0.f, 0.f};

    // Consume in issue order; c1-compute overlaps c2's in-flight returns.
#pragma unroll
    for (int m = 0; m < MM; ++m) {
        f4v s = s1[m];
        float lft = __shfl_up(s.w, 1);         // src[k0-1]; lane0: weight +0
        float rgt = __shfl_down(s.x, 1);       // src[k0+4]; lane63: weight -0
        float4 c  = cm[m];
        float wm_ = wmv[m];
        float w_w = l63 ? w2v[m] : wm_;        // k=255 knife edge
        acc1.x += wm_ * s.x + fabsf(c.x) * (((__float_as_int(c.x) >= 0) ? s.y : lft) - s.x);
        acc1.y += wm_ * s.y + fabsf(c.y) * (((__float_as_int(c.y) >= 0) ? s.z : s.x) - s.y);
        acc1.z += wm_ * s.z + fabsf(c.z) * (((__float_as_int(c.z) >= 0) ? s.w : s.y) - s.z);
        acc1.w += w_w * s.w + fabsf(c.w) * (((__float_as_int(c.w) >= 0) ? rgt : s.z) - s.w);
    }
#pragma unroll
    for (int m = 0; m < MM; ++m) {
        f4v s = s2[m];
        float lft = __shfl_up(s.w, 1);
        float rgt = __shfl_down(s.x, 1);
        float4 c  = cm[m];
        float wm_ = wmv[m];
        float w_w = l63 ? w2v[m] : wm_;
        acc2.x += wm_ * s.x + fabsf(c.x) * (((__float_as_int(c.x) >= 0) ? s.y : lft) - s.x);
        acc2.y += wm_ * s.y + fabsf(c.y) * (((__float_as_int(c.y) >= 0) ? s.z : s.x) - s.y);
        acc2.z += wm_ * s.z + fabsf(c.z) * (((__float_as_int(c.z) >= 0) ? s.w : s.y) - s.z);
        acc2.w += w_w * s.w + fabsf(c.w) * (((__float_as_int(c.w) >= 0) ? rgt : s.z) - s.w);
    }

    if (lane == 0) acc1.x = 0.001f;            // c1[:,:,0]  = C_CU_TARGET
    if (l63)       acc2.w = 0.0001f;           // c2[:,:,-1] = C_NI_TARGET

    nt4st(&out[((size_t)t * NOUTT + (size_t)i) * NOUTT + (size_t)k0],
          (f4v){acc1.x, acc1.y, acc1.z, acc1.w});
    nt4st(&out[((size_t)(NTT + t) * NOUTT + (size_t)i) * NOUTT + (size_t)k0],
          (f4v){acc2.x, acc2.y, acc2.z, acc2.w});
}

extern "C" void kernel_launch(void* const* d_in, const int* in_sizes, int n_in,
                              void* d_out, int out_size, void* d_ws, size_t ws_size,
                              hipStream_t stream) {
    const float* params = (const float*)d_in[0];
    const float* c1     = (const float*)d_in[1];
    const float* c2     = (const float*)d_in[2];
    const float* Wq     = (const float*)d_in[3];
    const float* bq     = (const float*)d_in[4];
    const float* Wk     = (const float*)d_in[5];
    const float* bk     = (const float*)d_in[6];
    float* out = (float*)d_out;

    ai_setup_kernel<<<dim3(MM), dim3(256), 0, stream>>>(params, Wq, bq, Wk, bk);
    ai_resample_kernel<<<dim3(NOUTT / 4, NTT), dim3(256), 0, stream>>>(c1, c2, out);
}